// Round 1
// baseline (1204.287 us; speedup 1.0000x reference)
//
#include <hip/hip_runtime.h>
#include <hip/hip_bf16.h>
#include <math.h>

#define TM 64
#define TN 64
#define TK 16

// C[M,N] = A[M,K] @ W[N,K]^T + bias[N]
__global__ __launch_bounds__(256) void gemm_bias(
    const float* __restrict__ A, const float* __restrict__ W,
    const float* __restrict__ bias, float* __restrict__ Out,
    int M, int N, int K) {
  __shared__ __attribute__((aligned(16))) float As[TK][TM + 4]; // [k][m], stride 68
  __shared__ __attribute__((aligned(16))) float Bs[TK][TN + 4]; // [k][n]

  const int tid = threadIdx.x;
  const int row0 = blockIdx.y * TM;
  const int col0 = blockIdx.x * TN;

  // loader mapping: 256 threads cover 64 rows x 16 k (float4 each)
  const int lr = tid >> 2;            // 0..63
  const int lk = (tid & 3) * 4;       // 0,4,8,12
  // compute mapping: 16x16 threads, 4x4 micro-tile
  const int ty = tid >> 4;            // 0..15
  const int tx = tid & 15;            // 0..15

  float acc[4][4];
#pragma unroll
  for (int i = 0; i < 4; ++i)
#pragma unroll
    for (int j = 0; j < 4; ++j) acc[i][j] = 0.f;

  for (int k0 = 0; k0 < K; k0 += TK) {
    const float4 a4 = *(const float4*)(A + (size_t)(row0 + lr) * K + k0 + lk);
    const float4 b4 = *(const float4*)(W + (size_t)(col0 + lr) * K + k0 + lk);
    __syncthreads();
    As[lk + 0][lr] = a4.x; As[lk + 1][lr] = a4.y;
    As[lk + 2][lr] = a4.z; As[lk + 3][lr] = a4.w;
    Bs[lk + 0][lr] = b4.x; Bs[lk + 1][lr] = b4.y;
    Bs[lk + 2][lr] = b4.z; Bs[lk + 3][lr] = b4.w;
    __syncthreads();
#pragma unroll
    for (int kk = 0; kk < TK; ++kk) {
      const float4 av = *(const float4*)&As[kk][ty * 4];
      const float4 bv = *(const float4*)&Bs[kk][tx * 4];
      acc[0][0] += av.x * bv.x; acc[0][1] += av.x * bv.y;
      acc[0][2] += av.x * bv.z; acc[0][3] += av.x * bv.w;
      acc[1][0] += av.y * bv.x; acc[1][1] += av.y * bv.y;
      acc[1][2] += av.y * bv.z; acc[1][3] += av.y * bv.w;
      acc[2][0] += av.z * bv.x; acc[2][1] += av.z * bv.y;
      acc[2][2] += av.z * bv.z; acc[2][3] += av.z * bv.w;
      acc[3][0] += av.w * bv.x; acc[3][1] += av.w * bv.y;
      acc[3][2] += av.w * bv.z; acc[3][3] += av.w * bv.w;
    }
  }

  const float4 bb = *(const float4*)(bias + col0 + tx * 4);
#pragma unroll
  for (int i = 0; i < 4; ++i) {
    float4 r;
    r.x = acc[i][0] + bb.x; r.y = acc[i][1] + bb.y;
    r.z = acc[i][2] + bb.z; r.w = acc[i][3] + bb.w;
    *(float4*)(Out + (size_t)(row0 + ty * 4 + i) * N + col0 + tx * 4) = r;
  }
}

__global__ void rope_table(float* __restrict__ cosT, float* __restrict__ sinT, int T) {
  int i = blockIdx.x * 256 + threadIdx.x;
  if (i >= T * 32) return;
  int t = i >> 5, j = i & 31;
  float inv = powf(10000.0f, -2.0f * (float)j / 64.0f);
  float ang = (float)t * inv;
  cosT[i] = cosf(ang);
  sinT[i] = sinf(ang);
}

// in-place RoPE on [B*T, C] buffer; pairs (2j,2j+1) within each 64-col head
__global__ void rope_apply(float* __restrict__ buf,
                           const float* __restrict__ cosT,
                           const float* __restrict__ sinT,
                           int total, int T) {
  int i = blockIdx.x * 256 + threadIdx.x;
  if (i >= total) return;
  int bt = i >> 9;        // C/2 = 512 pairs per row
  int c2 = i & 511;
  int t = bt % T;
  int j = c2 & 31;        // freq index within head
  float2 v = *(float2*)(buf + (size_t)i * 2);
  float c = cosT[t * 32 + j], s = sinT[t * 32 + j];
  float x0 = v.x, x1 = v.y;
  v.x = c * x0 - s * x1;
  v.y = s * x0 + c * x1;
  *(float2*)(buf + (size_t)i * 2) = v;
}

#define BQ 32
#define BK 32
#define HD 64

// causal flash attention, fp32. Q,K,V,Y layout [B, T, C] with head h at cols h*64..h*64+63
__global__ __launch_bounds__(256) void flash_attn(
    const float* __restrict__ Qg, const float* __restrict__ Kg,
    const float* __restrict__ Vg, float* __restrict__ Yg,
    int B, int Hn, int T) {
  __shared__ __attribute__((aligned(16))) float Qs[BQ][HD + 4];
  __shared__ __attribute__((aligned(16))) float Ks[BK][HD + 4];
  __shared__ __attribute__((aligned(16))) float Vs[BK][HD + 4];
  __shared__ float Ps[BQ][BK + 1];

  const int tid = threadIdx.x;
  const int qt = blockIdx.x, h = blockIdx.y, b = blockIdx.z;
  const int C = Hn * HD;
  const size_t base = ((size_t)b * T) * C + (size_t)h * HD;
  const int q0 = qt * BQ;

  // loader/compute mapping: row = tid/8 (0..31), group lane m8 = tid%8
  const int lrow = tid >> 3;
  const int m8 = tid & 7;
  const int ld0 = m8 * 8;

  { // stage Q tile
    const float* src = Qg + base + (size_t)(q0 + lrow) * C + ld0;
    *(float4*)&Qs[lrow][ld0] = *(const float4*)src;
    *(float4*)&Qs[lrow][ld0 + 4] = *(const float4*)(src + 4);
  }

  const int qr = lrow;     // this thread's q row
  float mrow = -INFINITY, lsum = 0.f;
  float o[8];
#pragma unroll
  for (int i = 0; i < 8; ++i) o[i] = 0.f;

  const int qg = q0 + qr;

  for (int kt = 0; kt <= qt; ++kt) {
    const int k0 = kt * BK;
    const float* kp = Kg + base + (size_t)(k0 + lrow) * C + ld0;
    const float* vp = Vg + base + (size_t)(k0 + lrow) * C + ld0;
    const float4 ka = *(const float4*)kp;
    const float4 kb = *(const float4*)(kp + 4);
    const float4 va = *(const float4*)vp;
    const float4 vb = *(const float4*)(vp + 4);
    __syncthreads();   // previous iteration done with Ks/Vs
    *(float4*)&Ks[lrow][ld0] = ka;
    *(float4*)&Ks[lrow][ld0 + 4] = kb;
    *(float4*)&Vs[lrow][ld0] = va;
    *(float4*)&Vs[lrow][ld0 + 4] = vb;
    __syncthreads();

    // scores: thread computes S[qr][m8 + 8n], n=0..3
    float s[4] = {0.f, 0.f, 0.f, 0.f};
#pragma unroll
    for (int d4 = 0; d4 < 16; ++d4) {
      const float4 qv = *(const float4*)&Qs[qr][d4 * 4];
#pragma unroll
      for (int n = 0; n < 4; ++n) {
        const float4 kv = *(const float4*)&Ks[m8 + 8 * n][d4 * 4];
        s[n] += qv.x * kv.x + qv.y * kv.y + qv.z * kv.z + qv.w * kv.w;
      }
    }
#pragma unroll
    for (int n = 0; n < 4; ++n) {
      const int kg = k0 + m8 + 8 * n;
      s[n] = (kg <= qg) ? s[n] * 0.125f : -1e10f;
    }

    // online softmax (8 lanes per row)
    float tmax = fmaxf(fmaxf(s[0], s[1]), fmaxf(s[2], s[3]));
    tmax = fmaxf(tmax, __shfl_xor(tmax, 1));
    tmax = fmaxf(tmax, __shfl_xor(tmax, 2));
    tmax = fmaxf(tmax, __shfl_xor(tmax, 4));
    const float mnew = fmaxf(mrow, tmax);
    const float corr = __expf(mrow - mnew);
    float psum = 0.f;
#pragma unroll
    for (int n = 0; n < 4; ++n) {
      const float p = __expf(s[n] - mnew);
      psum += p;
      Ps[qr][m8 + 8 * n] = p;
    }
    psum += __shfl_xor(psum, 1);
    psum += __shfl_xor(psum, 2);
    psum += __shfl_xor(psum, 4);
    lsum = lsum * corr + psum;
    mrow = mnew;
#pragma unroll
    for (int i = 0; i < 8; ++i) o[i] *= corr;

    __syncthreads();   // Ps visible

    // PV: thread owns O[qr][m8*8 .. m8*8+7]
#pragma unroll 8
    for (int k = 0; k < BK; ++k) {
      const float p = Ps[qr][k];
      const float4 v0 = *(const float4*)&Vs[k][m8 * 8];
      const float4 v1 = *(const float4*)&Vs[k][m8 * 8 + 4];
      o[0] += p * v0.x; o[1] += p * v0.y; o[2] += p * v0.z; o[3] += p * v0.w;
      o[4] += p * v1.x; o[5] += p * v1.y; o[6] += p * v1.z; o[7] += p * v1.w;
    }
  }

  const float inv = 1.0f / lsum;
  float* dst = Yg + base + (size_t)(q0 + qr) * C + m8 * 8;
  float4 r0, r1;
  r0.x = o[0] * inv; r0.y = o[1] * inv; r0.z = o[2] * inv; r0.w = o[3] * inv;
  r1.x = o[4] * inv; r1.y = o[5] * inv; r1.z = o[6] * inv; r1.w = o[7] * inv;
  *(float4*)dst = r0;
  *(float4*)(dst + 4) = r1;
}

extern "C" void kernel_launch(void* const* d_in, const int* in_sizes, int n_in,
                              void* d_out, int out_size, void* d_ws, size_t ws_size,
                              hipStream_t stream) {
  const float* x  = (const float*)d_in[0];
  const float* Wq = (const float*)d_in[1];
  const float* bq = (const float*)d_in[2];
  const float* Wk = (const float*)d_in[3];
  const float* bk = (const float*)d_in[4];
  const float* Wv = (const float*)d_in[5];
  const float* bv = (const float*)d_in[6];
  const float* Wp = (const float*)d_in[7];
  const float* bp = (const float*)d_in[8];
  float* out = (float*)d_out;
  float* ws = (float*)d_ws;

  const int B = 2, T = 2048, C = 1024, H = 16;
  const int M = B * T;            // 4096
  const size_t sz = (size_t)M * C; // 4,194,304 floats per buffer

  float* Q  = ws;
  float* Kb = ws + sz;
  float* Vb = ws + 2 * sz;
  float* Y  = ws + 3 * sz;
  float* cosT = ws + 4 * sz;
  float* sinT = cosT + (size_t)T * 32;

  rope_table<<<(T * 32 + 255) / 256, 256, 0, stream>>>(cosT, sinT, T);

  dim3 gg(C / TN, M / TM);
  gemm_bias<<<gg, 256, 0, stream>>>(x, Wq, bq, Q,  M, C, C);
  gemm_bias<<<gg, 256, 0, stream>>>(x, Wk, bk, Kb, M, C, C);
  gemm_bias<<<gg, 256, 0, stream>>>(x, Wv, bv, Vb, M, C, C);

  const int pairs = M * C / 2;
  rope_apply<<<pairs / 256, 256, 0, stream>>>(Q,  cosT, sinT, pairs, T);
  rope_apply<<<pairs / 256, 256, 0, stream>>>(Kb, cosT, sinT, pairs, T);

  dim3 fg(T / BQ, H, B);
  flash_attn<<<fg, 256, 0, stream>>>(Q, Kb, Vb, Y, B, H, T);

  gemm_bias<<<gg, 256, 0, stream>>>(Y, Wp, bp, out, M, C, C);
}

// Round 2
// 261.476 us; speedup vs baseline: 4.6057x; 4.6057x over previous
//
#include <hip/hip_runtime.h>
#include <math.h>

typedef unsigned short u16;
typedef unsigned int u32;
typedef __attribute__((ext_vector_type(8))) short short8;
typedef __attribute__((ext_vector_type(4))) float f32x4;
typedef __attribute__((ext_vector_type(4))) u16 u16x4;

#define AS1 __attribute__((address_space(1)))
#define AS3 __attribute__((address_space(3)))

__device__ __forceinline__ u16 f2bf(float f) {
  union { float f; u32 i; } u; u.f = f;
  u32 r = u.i + 0x7FFFu + ((u.i >> 16) & 1u);
  return (u16)(r >> 16);
}

__device__ __forceinline__ void gl_lds16(const void* g, void* l) {
  __builtin_amdgcn_global_load_lds((const AS1 u32*)g, (AS3 u32*)l, 16, 0, 0);
}

// ---------------- converts ----------------
__global__ void cvt_bf16(const float* __restrict__ in, u16* __restrict__ out, int n4) {
  int i = blockIdx.x * 256 + threadIdx.x;
  if (i >= n4) return;
  float4 v = ((const float4*)in)[i];
  u16x4 o = { f2bf(v.x), f2bf(v.y), f2bf(v.z), f2bf(v.w) };
  ((u16x4*)out)[i] = o;
}

__global__ void rope_table(float* __restrict__ cosT, float* __restrict__ sinT, int T) {
  int i = blockIdx.x * 256 + threadIdx.x;
  if (i >= T * 32) return;
  int t = i >> 5, j = i & 31;
  float inv = powf(10000.0f, -(float)j / 32.0f);
  float ang = (float)t * inv;
  cosT[i] = cosf(ang);
  sinT[i] = sinf(ang);
}

// read fp32 [M][1024], apply RoPE (head_dim 64), write bf16
__global__ void rope_cvt(const float* __restrict__ in, u16* __restrict__ out,
                         const float* __restrict__ cosT, const float* __restrict__ sinT,
                         int n4) {
  int i = blockIdx.x * 256 + threadIdx.x;
  if (i >= n4) return;
  int row = i >> 8;            // C/4 = 256 float4 per row
  int t = row & 2047;          // T = 2048
  int j = (((i & 255) * 4) & 63) >> 1;   // freq index of first pair
  float4 v = ((const float4*)in)[i];
  float c0 = cosT[t * 32 + j],     s0 = sinT[t * 32 + j];
  float c1 = cosT[t * 32 + j + 1], s1 = sinT[t * 32 + j + 1];
  u16x4 o = { f2bf(c0 * v.x - s0 * v.y), f2bf(s0 * v.x + c0 * v.y),
              f2bf(c1 * v.z - s1 * v.w), f2bf(s1 * v.z + c1 * v.w) };
  ((u16x4*)out)[i] = o;
}

// ---------------- bf16 MFMA GEMM:  Out[M,N] = A[M,K] @ W[N,K]^T + bias ----------------
template<int OUT_BF16>
__global__ __launch_bounds__(256, 2) void gemm_mfma(
    const u16* __restrict__ A, const u16* __restrict__ W,
    const float* __restrict__ bias, float* __restrict__ OutF, u16* __restrict__ OutB,
    int M, int N, int K) {
  __shared__ __attribute__((aligned(16))) u16 As[128 * 32];
  __shared__ __attribute__((aligned(16))) u16 Bs[128 * 32];
  const int tid = threadIdx.x;
  const int lane = tid & 63;
  const int hi = lane >> 4, c = lane & 15;
  const int w = tid >> 6, wm = w >> 1, wn = w & 1;
  const int row0 = blockIdx.y * 128, col0 = blockIdx.x * 128;

  const int lr = tid >> 2;            // 0..63
  const int lk = (tid & 3) * 8;       // ushort col 0,8,16,24
  const u16* Ag0 = A + (size_t)(row0 + lr) * K + lk;
  const u16* Ag1 = A + (size_t)(row0 + 64 + lr) * K + lk;
  const u16* Wg0 = W + (size_t)(col0 + lr) * K + lk;
  const u16* Wg1 = W + (size_t)(col0 + 64 + lr) * K + lk;
  u16* Al0 = As + tid * 8;
  u16* Al1 = As + 2048 + tid * 8;
  u16* Bl0 = Bs + tid * 8;
  u16* Bl1 = Bs + 2048 + tid * 8;

  f32x4 acc[4][4];
#pragma unroll
  for (int m = 0; m < 4; ++m)
#pragma unroll
    for (int n = 0; n < 4; ++n) acc[m][n] = f32x4{0.f, 0.f, 0.f, 0.f};

  for (int k0 = 0; k0 < K; k0 += 32) {
    __syncthreads();
    gl_lds16(Ag0 + k0, Al0);
    gl_lds16(Ag1 + k0, Al1);
    gl_lds16(Wg0 + k0, Bl0);
    gl_lds16(Wg1 + k0, Bl1);
    __syncthreads();
    short8 a[4], b[4];
#pragma unroll
    for (int m = 0; m < 4; ++m)
      a[m] = *(const short8*)(As + (wm * 64 + m * 16 + c) * 32 + hi * 8);
#pragma unroll
    for (int n = 0; n < 4; ++n)
      b[n] = *(const short8*)(Bs + (wn * 64 + n * 16 + c) * 32 + hi * 8);
#pragma unroll
    for (int m = 0; m < 4; ++m)
#pragma unroll
      for (int n = 0; n < 4; ++n)
        acc[m][n] = __builtin_amdgcn_mfma_f32_16x16x32_bf16(a[m], b[n], acc[m][n], 0, 0, 0);
  }

#pragma unroll
  for (int n = 0; n < 4; ++n) {
    const int col = col0 + wn * 64 + n * 16 + c;
    const float bb = bias[col];
#pragma unroll
    for (int m = 0; m < 4; ++m) {
      const int rw = row0 + wm * 64 + m * 16 + hi * 4;
#pragma unroll
      for (int r = 0; r < 4; ++r) {
        float v = acc[m][n][r] + bb;
        if (OUT_BF16) OutB[(size_t)(rw + r) * N + col] = f2bf(v);
        else          OutF[(size_t)(rw + r) * N + col] = v;
      }
    }
  }
}

// ---------------- MFMA causal flash attention ----------------
// 4 waves/block, each owns 16 q rows; 64 q rows/block, 64-key tiles.
__global__ __launch_bounds__(256, 2) void flash_mfma(
    const u16* __restrict__ Qb, const u16* __restrict__ Kb,
    const u16* __restrict__ Vb, u16* __restrict__ Yb) {
  const int T = 2048, C = 1024;
  __shared__ __attribute__((aligned(16))) u16 Ks[64 * 64];
  __shared__ __attribute__((aligned(16))) u16 Vt[64 * 64];     // transposed V: [d][key]
  __shared__ __attribute__((aligned(16))) u16 Ps[4][16 * 64];  // per-wave P

  const int tid = threadIdx.x;
  const int lane = tid & 63;
  const int hi = lane >> 4, cc = lane & 15;
  const int w = tid >> 6;
  const int qt = (int)gridDim.x - 1 - (int)blockIdx.x;  // longest blocks first
  const int bh = blockIdx.y;
  const size_t hbase = (size_t)(bh >> 4) * T * C + (size_t)(bh & 15) * 64;
  const int q0 = qt * 64;

  // Q a-frags (A row = lane&15, k = d = hi*8+j [+32])
  short8 qa0, qa1;
  {
    const u16* qp = Qb + hbase + (size_t)(q0 + w * 16 + cc) * C + hi * 8;
    qa0 = *(const short8*)qp;
    qa1 = *(const short8*)(qp + 32);
  }

  f32x4 o[4];
#pragma unroll
  for (int nt = 0; nt < 4; ++nt) o[nt] = f32x4{0.f, 0.f, 0.f, 0.f};
  f32x4 mrow = f32x4{-INFINITY, -INFINITY, -INFINITY, -INFINITY};
  f32x4 lsum = f32x4{0.f, 0.f, 0.f, 0.f};

  // staging maps
  const int kkey = tid >> 2, kd0 = (tid & 3) * 16;        // K: coalesced rows
  const int vkp = tid & 31, vd0 = (tid >> 5) * 8;         // V: key pair 2vkp,2vkp+1

  const u16* kgb  = Kb + hbase + (size_t)kkey * C + kd0;
  const u16* vgb0 = Vb + hbase + (size_t)(2 * vkp) * C + vd0;
  const u16* vgb1 = Vb + hbase + (size_t)(2 * vkp + 1) * C + vd0;

  char* KsB = (char*)Ks;
  char* VtB = (char*)Vt;
  char* PsB = (char*)(Ps[w]);

  for (int kt = 0; kt <= qt; ++kt) {
    const size_t koff = (size_t)(kt * 64) * C;
    short8 kv0 = *(const short8*)(kgb + koff);
    short8 kv1 = *(const short8*)(kgb + koff + 8);
    short8 vv0 = *(const short8*)(vgb0 + koff);
    short8 vv1 = *(const short8*)(vgb1 + koff);

    __syncthreads();   // everyone done reading previous K/Vt
    {
      const int sw = (kkey & 7) << 4;
      const int base = kkey * 128 + kd0 * 2;
      *(short8*)(KsB + (base ^ sw)) = kv0;
      *(short8*)(KsB + ((base + 16) ^ sw)) = kv1;
    }
#pragma unroll
    for (int i = 0; i < 8; ++i) {
      const int d = vd0 + i;
      const u32 pv = (u32)(u16)vv0[i] | ((u32)(u16)vv1[i] << 16);
      *(u32*)(VtB + ((d * 128 + vkp * 4) ^ ((((d >> 3) ^ d) & 7) << 4))) = pv;
    }
    __syncthreads();

    const bool diag = (kt == qt);

    // S = Q K^T
    f32x4 s[4];
#pragma unroll
    for (int nt = 0; nt < 4; ++nt) {
      const int kr = nt * 16 + cc;
      const int sw = (kr & 7) << 4;
      short8 b0 = *(const short8*)(KsB + ((kr * 128 + hi * 16) ^ sw));
      short8 b1 = *(const short8*)(KsB + ((kr * 128 + 64 + hi * 16) ^ sw));
      f32x4 z = f32x4{0.f, 0.f, 0.f, 0.f};
      z = __builtin_amdgcn_mfma_f32_16x16x32_bf16(qa0, b0, z, 0, 0, 0);
      z = __builtin_amdgcn_mfma_f32_16x16x32_bf16(qa1, b1, z, 0, 0, 0);
      s[nt] = z;
    }

    if (diag) {
#pragma unroll
      for (int nt = 0; nt < 4; ++nt) {
        const int key = nt * 16 + cc;          // k0 == q0 on diagonal
#pragma unroll
        for (int r = 0; r < 4; ++r) {
          const int qr = w * 16 + hi * 4 + r;
          s[nt][r] = (key <= qr) ? s[nt][r] * 0.125f : -1e10f;
        }
      }
    } else {
#pragma unroll
      for (int nt = 0; nt < 4; ++nt) s[nt] = s[nt] * 0.125f;
    }

    // online softmax (rows live at r = reg idx, shared across the 16-lane group)
    f32x4 tm;
#pragma unroll
    for (int r = 0; r < 4; ++r)
      tm[r] = fmaxf(fmaxf(s[0][r], s[1][r]), fmaxf(s[2][r], s[3][r]));
#pragma unroll
    for (int msk = 1; msk <= 8; msk <<= 1) {
#pragma unroll
      for (int r = 0; r < 4; ++r) tm[r] = fmaxf(tm[r], __shfl_xor(tm[r], msk));
    }
    f32x4 mnew, corr;
#pragma unroll
    for (int r = 0; r < 4; ++r) mnew[r] = fmaxf(mrow[r], tm[r]);
#pragma unroll
    for (int r = 0; r < 4; ++r) corr[r] = __expf(mrow[r] - mnew[r]);
    float p[4][4];
    f32x4 psum = f32x4{0.f, 0.f, 0.f, 0.f};
#pragma unroll
    for (int nt = 0; nt < 4; ++nt)
#pragma unroll
      for (int r = 0; r < 4; ++r) {
        float e = __expf(s[nt][r] - mnew[r]);
        p[nt][r] = e;
        psum[r] += e;
      }
#pragma unroll
    for (int msk = 1; msk <= 8; msk <<= 1) {
#pragma unroll
      for (int r = 0; r < 4; ++r) psum[r] += __shfl_xor(psum[r], msk);
    }
#pragma unroll
    for (int r = 0; r < 4; ++r) {
      lsum[r] = lsum[r] * corr[r] + psum[r];
      mrow[r] = mnew[r];
    }
#pragma unroll
    for (int nt = 0; nt < 4; ++nt) o[nt] *= corr;

    // stage P (bf16) into per-wave LDS (D-layout -> A-layout transpose)
#pragma unroll
    for (int nt = 0; nt < 4; ++nt)
#pragma unroll
      for (int r = 0; r < 4; ++r) {
        const int pr = hi * 4 + r;
        *(u16*)(PsB + ((pr * 128 + (nt * 16 + cc) * 2) ^ ((pr & 7) << 4))) = f2bf(p[nt][r]);
      }

    // O += P V
#pragma unroll
    for (int kc = 0; kc < 2; ++kc) {
      short8 pa = *(const short8*)(PsB + ((cc * 128 + kc * 64 + hi * 16) ^ ((cc & 7) << 4)));
#pragma unroll
      for (int nt = 0; nt < 4; ++nt) {
        const int vr = nt * 16 + cc;
        short8 vb = *(const short8*)(VtB + ((vr * 128 + kc * 64 + hi * 16) ^ ((((vr >> 3) ^ vr) & 7) << 4)));
        o[nt] = __builtin_amdgcn_mfma_f32_16x16x32_bf16(pa, vb, o[nt], 0, 0, 0);
      }
    }
  }

  f32x4 inv;
#pragma unroll
  for (int r = 0; r < 4; ++r) inv[r] = 1.0f / lsum[r];
#pragma unroll
  for (int nt = 0; nt < 4; ++nt) {
#pragma unroll
    for (int r = 0; r < 4; ++r) {
      const int qrow = q0 + w * 16 + hi * 4 + r;
      Yb[hbase + (size_t)qrow * C + nt * 16 + cc] = f2bf(o[nt][r] * inv[r]);
    }
  }
}

extern "C" void kernel_launch(void* const* d_in, const int* in_sizes, int n_in,
                              void* d_out, int out_size, void* d_ws, size_t ws_size,
                              hipStream_t stream) {
  const float* x  = (const float*)d_in[0];
  const float* Wq = (const float*)d_in[1];
  const float* bq = (const float*)d_in[2];
  const float* Wk = (const float*)d_in[3];
  const float* bk = (const float*)d_in[4];
  const float* Wv = (const float*)d_in[5];
  const float* bv = (const float*)d_in[6];
  const float* Wp = (const float*)d_in[7];
  const float* bp = (const float*)d_in[8];
  float* out = (float*)d_out;

  const int B = 2, T = 2048, C = 1024;
  const int M = B * T;                 // 4096
  const size_t MC = (size_t)M * C;     // 4194304
  const size_t CC = (size_t)C * C;

  char* p = (char*)d_ws;
  float* Pf  = (float*)p;  p += MC * 4;     // fp32 staging (reused for Q then K)
  u16* xb    = (u16*)p;    p += MC * 2;
  u16* Wqb   = (u16*)p;    p += CC * 2;
  u16* Wkb   = (u16*)p;    p += CC * 2;
  u16* Wvb   = (u16*)p;    p += CC * 2;
  u16* Wpb   = (u16*)p;    p += CC * 2;
  u16* Qbb   = (u16*)p;    p += MC * 2;
  u16* Kbb   = (u16*)p;    p += MC * 2;
  u16* Vbb   = (u16*)p;    p += MC * 2;
  u16* Ybb   = (u16*)p;    p += MC * 2;
  float* cosT = (float*)p; p += (size_t)T * 32 * 4;
  float* sinT = (float*)p; p += (size_t)T * 32 * 4;

  rope_table<<<T * 32 / 256, 256, 0, stream>>>(cosT, sinT, T);
  cvt_bf16<<<(int)(MC / 4 / 256), 256, 0, stream>>>(x, xb, (int)(MC / 4));
  cvt_bf16<<<(int)(CC / 4 / 256), 256, 0, stream>>>(Wq, Wqb, (int)(CC / 4));
  cvt_bf16<<<(int)(CC / 4 / 256), 256, 0, stream>>>(Wk, Wkb, (int)(CC / 4));
  cvt_bf16<<<(int)(CC / 4 / 256), 256, 0, stream>>>(Wv, Wvb, (int)(CC / 4));
  cvt_bf16<<<(int)(CC / 4 / 256), 256, 0, stream>>>(Wp, Wpb, (int)(CC / 4));

  dim3 gg(C / 128, M / 128);
  gemm_mfma<0><<<gg, 256, 0, stream>>>(xb, Wqb, bq, Pf, nullptr, M, C, C);
  rope_cvt<<<(int)(MC / 4 / 256), 256, 0, stream>>>(Pf, Qbb, cosT, sinT, (int)(MC / 4));
  gemm_mfma<0><<<gg, 256, 0, stream>>>(xb, Wkb, bk, Pf, nullptr, M, C, C);
  rope_cvt<<<(int)(MC / 4 / 256), 256, 0, stream>>>(Pf, Kbb, cosT, sinT, (int)(MC / 4));
  gemm_mfma<1><<<gg, 256, 0, stream>>>(xb, Wvb, bv, nullptr, Vbb, M, C, C);

  dim3 fg(T / 64, B * 16);
  flash_mfma<<<fg, 256, 0, stream>>>(Qbb, Kbb, Vbb, Ybb);

  gemm_mfma<0><<<gg, 256, 0, stream>>>(Ybb, Wpb, bp, out, nullptr, M, C, C);
}

// Round 3
// 156.474 us; speedup vs baseline: 7.6964x; 1.6710x over previous
//
#include <hip/hip_runtime.h>
#include <math.h>

typedef unsigned short u16;
typedef unsigned int u32;
typedef __attribute__((ext_vector_type(8))) short short8;
typedef __attribute__((ext_vector_type(4))) float f32x4;
typedef __attribute__((ext_vector_type(4))) u16 u16x4;

#define AS1 __attribute__((address_space(1)))
#define AS3 __attribute__((address_space(3)))

__device__ __forceinline__ u16 f2bf(float f) {
  union { float f; u32 i; } u; u.f = f;
  u32 r = u.i + 0x7FFFu + ((u.i >> 16) & 1u);
  return (u16)(r >> 16);
}

__device__ __forceinline__ void gl_lds16(const void* g, void* l) {
  __builtin_amdgcn_global_load_lds((const AS1 u32*)g, (AS3 u32*)l, 16, 0, 0);
}

// ---------------- RoPE table ----------------
__global__ void rope_table(float* __restrict__ cosT, float* __restrict__ sinT, int T) {
  int i = blockIdx.x * 256 + threadIdx.x;
  if (i >= T * 32) return;
  int t = i >> 5, j = i & 31;
  float inv = powf(10000.0f, -(float)j / 32.0f);
  float ang = (float)t * inv;
  cosT[i] = cosf(ang);
  sinT[i] = sinf(ang);
}

// ---------------- fused fp32 -> bf16 convert (x + 4 weights) ----------------
__global__ void cvt_all(const float* __restrict__ x,
                        const float* __restrict__ Wq, const float* __restrict__ Wk,
                        const float* __restrict__ Wv, const float* __restrict__ Wp,
                        u16* __restrict__ xb,
                        u16* __restrict__ Wqb, u16* __restrict__ Wkb,
                        u16* __restrict__ Wvb, u16* __restrict__ Wpb,
                        int n4x) {
  int i = blockIdx.x * 256 + threadIdx.x;
  const float* src; u16* dst; int off;
  if (i < n4x) { src = x; dst = xb; off = i; }
  else {
    int wi = i - n4x;
    int sel = wi >> 18;            // CC/4 = 2^18
    off = wi & ((1 << 18) - 1);
    src = sel == 0 ? Wq : sel == 1 ? Wk : sel == 2 ? Wv : Wp;
    dst = sel == 0 ? Wqb : sel == 1 ? Wkb : sel == 2 ? Wvb : Wpb;
  }
  float4 v = ((const float4*)src)[off];
  u16x4 o = { f2bf(v.x), f2bf(v.y), f2bf(v.z), f2bf(v.w) };
  ((u16x4*)dst)[off] = o;
}

// ---------------- fused QKV GEMM (bf16 MFMA) with RoPE epilogue ----------------
// grid (24, 32): blockIdx.x = sel*8 + col-tile. Out = bf16 Q/K (roped) or V.
__global__ __launch_bounds__(256, 2) void gemm_qkv(
    const u16* __restrict__ xb,
    const u16* __restrict__ Wqb, const u16* __restrict__ Wkb, const u16* __restrict__ Wvb,
    const float* __restrict__ bq, const float* __restrict__ bk, const float* __restrict__ bv,
    const float* __restrict__ cosT, const float* __restrict__ sinT,
    u16* __restrict__ Qb, u16* __restrict__ Kb, u16* __restrict__ Vb) {
  const int K = 1024, N = 1024;
  __shared__ __attribute__((aligned(16))) u16 As[128 * 32];
  __shared__ __attribute__((aligned(16))) u16 Bs[128 * 32];
  const int tid = threadIdx.x;
  const int lane = tid & 63;
  const int hi = lane >> 4, cc = lane & 15;
  const int w = tid >> 6, wm = w >> 1, wn = w & 1;
  const int sel = blockIdx.x >> 3;
  const int row0 = blockIdx.y * 128, col0 = (blockIdx.x & 7) * 128;
  const u16* W = sel == 0 ? Wqb : sel == 1 ? Wkb : Wvb;
  const float* bias = sel == 0 ? bq : sel == 1 ? bk : bv;
  u16* Out = sel == 0 ? Qb : sel == 1 ? Kb : Vb;

  const int lr = tid >> 2;
  const int lk = (tid & 3) * 8;
  const u16* Ag0 = xb + (size_t)(row0 + lr) * K + lk;
  const u16* Ag1 = xb + (size_t)(row0 + 64 + lr) * K + lk;
  const u16* Wg0 = W + (size_t)(col0 + lr) * K + lk;
  const u16* Wg1 = W + (size_t)(col0 + 64 + lr) * K + lk;
  u16* Al0 = As + tid * 8;
  u16* Al1 = As + 2048 + tid * 8;
  u16* Bl0 = Bs + tid * 8;
  u16* Bl1 = Bs + 2048 + tid * 8;

  f32x4 acc[4][4];
#pragma unroll
  for (int m = 0; m < 4; ++m)
#pragma unroll
    for (int n = 0; n < 4; ++n) acc[m][n] = f32x4{0.f, 0.f, 0.f, 0.f};

  for (int k0 = 0; k0 < K; k0 += 32) {
    __syncthreads();
    gl_lds16(Ag0 + k0, Al0);
    gl_lds16(Ag1 + k0, Al1);
    gl_lds16(Wg0 + k0, Bl0);
    gl_lds16(Wg1 + k0, Bl1);
    __syncthreads();
    short8 a[4], b[4];
#pragma unroll
    for (int m = 0; m < 4; ++m)
      a[m] = *(const short8*)(As + (wm * 64 + m * 16 + cc) * 32 + hi * 8);
#pragma unroll
    for (int n = 0; n < 4; ++n)
      b[n] = *(const short8*)(Bs + (wn * 64 + n * 16 + cc) * 32 + hi * 8);
#pragma unroll
    for (int m = 0; m < 4; ++m)
#pragma unroll
      for (int n = 0; n < 4; ++n)
        acc[m][n] = __builtin_amdgcn_mfma_f32_16x16x32_bf16(a[m], b[n], acc[m][n], 0, 0, 0);
  }

  if (sel < 2) {
    // RoPE epilogue: pairs are adjacent columns -> adjacent lanes (cc parity)
#pragma unroll
    for (int n = 0; n < 4; ++n) {
      const int col = col0 + wn * 64 + n * 16 + cc;
      const int j = (col & 63) >> 1;
      const float bb = bias[col];
#pragma unroll
      for (int m = 0; m < 4; ++m) {
        const int rw = row0 + wm * 64 + m * 16 + hi * 4;
#pragma unroll
        for (int r = 0; r < 4; ++r) {
          const int row = rw + r;
          const int t = row & 2047;
          float v = acc[m][n][r] + bb;
          float pv = __shfl_xor(v, 1);
          float c = cosT[t * 32 + j], s = sinT[t * 32 + j];
          float oo = (cc & 1) ? (s * pv + c * v) : (c * v - s * pv);
          Out[(size_t)row * N + col] = f2bf(oo);
        }
      }
    }
  } else {
#pragma unroll
    for (int n = 0; n < 4; ++n) {
      const int col = col0 + wn * 64 + n * 16 + cc;
      const float bb = bias[col];
#pragma unroll
      for (int m = 0; m < 4; ++m) {
        const int rw = row0 + wm * 64 + m * 16 + hi * 4;
#pragma unroll
        for (int r = 0; r < 4; ++r)
          Out[(size_t)(rw + r) * N + col] = f2bf(acc[m][n][r] + bb);
      }
    }
  }
}

// ---------------- MFMA causal flash attention (swapped QK^T) ----------------
__global__ __launch_bounds__(256, 3) void flash_mfma(
    const u16* __restrict__ Qb, const u16* __restrict__ Kb,
    const u16* __restrict__ Vb, u16* __restrict__ Yb) {
  const int T = 2048, C = 1024;
  __shared__ __attribute__((aligned(16))) u16 Ks[64 * 64];
  __shared__ __attribute__((aligned(16))) u16 Vt[64 * 64];     // [d][key]
  __shared__ __attribute__((aligned(16))) u16 Ps[4][16 * 64];  // per-wave P[q][key]

  const int tid = threadIdx.x;
  const int lane = tid & 63;
  const int hi = lane >> 4, cc = lane & 15;
  const int w = tid >> 6;
  const int qt = (int)gridDim.x - 1 - (int)blockIdx.x;  // longest first
  const int bh = blockIdx.y;
  const size_t hbase = (size_t)(bh >> 4) * T * C + (size_t)(bh & 15) * 64;
  const int q0 = qt * 64;
  const int q0w = q0 + w * 16;

  // Q fragment (B-operand: col = q = lane&15, k = d = hi*8+j)
  short8 qa0, qa1;
  {
    const u16* qp = Qb + hbase + (size_t)(q0w + cc) * C + hi * 8;
    qa0 = *(const short8*)qp;
    qa1 = *(const short8*)(qp + 32);
  }

  f32x4 o[4];
#pragma unroll
  for (int nt = 0; nt < 4; ++nt) o[nt] = f32x4{0.f, 0.f, 0.f, 0.f};
  float mrow = -INFINITY, lsum = 0.f;

  const int kkey = tid >> 2, kd0 = (tid & 3) * 16;
  const int vkp = tid & 31, vd0 = (tid >> 5) * 8;
  const u16* kgb = Kb + hbase + (size_t)kkey * C + kd0;
  const u16* vg0 = Vb + hbase + (size_t)(2 * vkp) * C + vd0;
  const u16* vg1 = Vb + hbase + (size_t)(2 * vkp + 1) * C + vd0;
  char* KsB = (char*)Ks;
  char* VtB = (char*)Vt;
  char* PsB = (char*)(Ps[w]);

  // prefetch tile 0
  short8 kv0 = *(const short8*)kgb;
  short8 kv1 = *(const short8*)(kgb + 8);
  short8 vv0 = *(const short8*)vg0;
  short8 vv1 = *(const short8*)vg1;

  for (int kt = 0; kt <= qt; ++kt) {
    __syncthreads();   // prior reads of Ks/Vt done
    {
      const int sw = (kkey & 7) << 4;
      const int base = kkey * 128 + kd0 * 2;
      *(short8*)(KsB + (base ^ sw)) = kv0;
      *(short8*)(KsB + ((base + 16) ^ sw)) = kv1;
    }
#pragma unroll
    for (int i = 0; i < 8; ++i) {
      const int d = vd0 + i;
      const u32 pv = (u32)(u16)vv0[i] | ((u32)(u16)vv1[i] << 16);
      *(u32*)(VtB + ((d * 128 + vkp * 4) ^ ((((d >> 3) ^ d) & 7) << 4))) = pv;
    }
    {  // prefetch next tile (clamped; overlaps with compute below)
      const size_t koff = (size_t)((kt < qt ? kt + 1 : qt) * 64) * C;
      kv0 = *(const short8*)(kgb + koff);
      kv1 = *(const short8*)(kgb + koff + 8);
      vv0 = *(const short8*)(vg0 + koff);
      vv1 = *(const short8*)(vg1 + koff);
    }
    __syncthreads();

    // S^T = K Q^T : lane holds 16 keys for its q = cc
    f32x4 s[4];
#pragma unroll
    for (int nt = 0; nt < 4; ++nt) {
      const int kr = nt * 16 + cc;
      const int sw2 = (kr & 7) << 4;
      short8 b0 = *(const short8*)(KsB + ((kr * 128 + hi * 16) ^ sw2));
      short8 b1 = *(const short8*)(KsB + ((kr * 128 + 64 + hi * 16) ^ sw2));
      f32x4 z = f32x4{0.f, 0.f, 0.f, 0.f};
      z = __builtin_amdgcn_mfma_f32_16x16x32_bf16(b0, qa0, z, 0, 0, 0);
      z = __builtin_amdgcn_mfma_f32_16x16x32_bf16(b1, qa1, z, 0, 0, 0);
      s[nt] = z;
    }

    if (kt == qt) {
#pragma unroll
      for (int nt = 0; nt < 4; ++nt)
#pragma unroll
        for (int r = 0; r < 4; ++r) {
          const int key = nt * 16 + hi * 4 + r;
          s[nt][r] = (key <= w * 16 + cc) ? s[nt][r] * 0.125f : -1e10f;
        }
    } else {
#pragma unroll
      for (int nt = 0; nt < 4; ++nt) s[nt] = s[nt] * 0.125f;
    }

    // in-lane softmax over 16 keys + 2 cross-hi shuffles
    float tm = s[0][0];
#pragma unroll
    for (int nt = 0; nt < 4; ++nt)
#pragma unroll
      for (int r = 0; r < 4; ++r) tm = fmaxf(tm, s[nt][r]);
    tm = fmaxf(tm, __shfl_xor(tm, 16));
    tm = fmaxf(tm, __shfl_xor(tm, 32));
    const float mnew = fmaxf(mrow, tm);
    const float corr = __expf(mrow - mnew);
    float p[4][4];
    float psum = 0.f;
#pragma unroll
    for (int nt = 0; nt < 4; ++nt)
#pragma unroll
      for (int r = 0; r < 4; ++r) {
        float e = __expf(s[nt][r] - mnew);
        p[nt][r] = e;
        psum += e;
      }
    psum += __shfl_xor(psum, 16);
    psum += __shfl_xor(psum, 32);
    lsum = lsum * corr + psum;
    mrow = mnew;
#pragma unroll
    for (int nt = 0; nt < 4; ++nt) o[nt] *= corr;

    // stage P[q][key]: 4x ds_write_b64, swizzled
#pragma unroll
    for (int nt = 0; nt < 4; ++nt) {
      u16x4 pk = { f2bf(p[nt][0]), f2bf(p[nt][1]), f2bf(p[nt][2]), f2bf(p[nt][3]) };
      *(u16x4*)(PsB + ((cc * 128 + nt * 32 + hi * 8) ^ ((cc & 7) << 4))) = pk;
    }

    // O^T += V^T P^T
#pragma unroll
    for (int kc = 0; kc < 2; ++kc) {
      short8 pa = *(const short8*)(PsB + ((cc * 128 + kc * 64 + hi * 16) ^ ((cc & 7) << 4)));
#pragma unroll
      for (int nt = 0; nt < 4; ++nt) {
        const int vr = nt * 16 + cc;
        short8 vb = *(const short8*)(VtB + ((vr * 128 + kc * 64 + hi * 16) ^ ((((vr >> 3) ^ vr) & 7) << 4)));
        o[nt] = __builtin_amdgcn_mfma_f32_16x16x32_bf16(vb, pa, o[nt], 0, 0, 0);
      }
    }
  }

  const float invl = 1.0f / lsum;
#pragma unroll
  for (int nt = 0; nt < 4; ++nt) {
    u16x4 y = { f2bf(o[nt][0] * invl), f2bf(o[nt][1] * invl),
                f2bf(o[nt][2] * invl), f2bf(o[nt][3] * invl) };
    *(u16x4*)(Yb + hbase + (size_t)(q0w + cc) * C + nt * 16 + hi * 4) = y;
  }
}

// ---------------- proj GEMM: BN=64, fp32 out ----------------
__global__ __launch_bounds__(256, 2) void gemm_proj(
    const u16* __restrict__ A, const u16* __restrict__ W,
    const float* __restrict__ bias, float* __restrict__ Out) {
  const int K = 1024, N = 1024;
  __shared__ __attribute__((aligned(16))) u16 As[128 * 32];
  __shared__ __attribute__((aligned(16))) u16 Bs[64 * 32];
  const int tid = threadIdx.x;
  const int lane = tid & 63;
  const int hi = lane >> 4, cc = lane & 15;
  const int w = tid >> 6, wm = w >> 1, wn = w & 1;
  const int row0 = blockIdx.y * 128, col0 = blockIdx.x * 64;

  const int lr = tid >> 2;
  const int lk = (tid & 3) * 8;
  const u16* Ag0 = A + (size_t)(row0 + lr) * K + lk;
  const u16* Ag1 = A + (size_t)(row0 + 64 + lr) * K + lk;
  const u16* Wg0 = W + (size_t)(col0 + lr) * K + lk;
  u16* Al0 = As + tid * 8;
  u16* Al1 = As + 2048 + tid * 8;
  u16* Bl0 = Bs + tid * 8;

  f32x4 acc[4][2];
#pragma unroll
  for (int m = 0; m < 4; ++m)
#pragma unroll
    for (int n = 0; n < 2; ++n) acc[m][n] = f32x4{0.f, 0.f, 0.f, 0.f};

  for (int k0 = 0; k0 < K; k0 += 32) {
    __syncthreads();
    gl_lds16(Ag0 + k0, Al0);
    gl_lds16(Ag1 + k0, Al1);
    gl_lds16(Wg0 + k0, Bl0);
    __syncthreads();
    short8 a[4], b[2];
#pragma unroll
    for (int m = 0; m < 4; ++m)
      a[m] = *(const short8*)(As + (wm * 64 + m * 16 + cc) * 32 + hi * 8);
#pragma unroll
    for (int n = 0; n < 2; ++n)
      b[n] = *(const short8*)(Bs + (wn * 32 + n * 16 + cc) * 32 + hi * 8);
#pragma unroll
    for (int m = 0; m < 4; ++m)
#pragma unroll
      for (int n = 0; n < 2; ++n)
        acc[m][n] = __builtin_amdgcn_mfma_f32_16x16x32_bf16(a[m], b[n], acc[m][n], 0, 0, 0);
  }

#pragma unroll
  for (int n = 0; n < 2; ++n) {
    const int col = col0 + wn * 32 + n * 16 + cc;
    const float bb = bias[col];
#pragma unroll
    for (int m = 0; m < 4; ++m) {
      const int rw = row0 + wm * 64 + m * 16 + hi * 4;
#pragma unroll
      for (int r = 0; r < 4; ++r)
        Out[(size_t)(rw + r) * N + col] = acc[m][n][r] + bb;
    }
  }
}

extern "C" void kernel_launch(void* const* d_in, const int* in_sizes, int n_in,
                              void* d_out, int out_size, void* d_ws, size_t ws_size,
                              hipStream_t stream) {
  const float* x  = (const float*)d_in[0];
  const float* Wq = (const float*)d_in[1];
  const float* bq = (const float*)d_in[2];
  const float* Wk = (const float*)d_in[3];
  const float* bk = (const float*)d_in[4];
  const float* Wv = (const float*)d_in[5];
  const float* bv = (const float*)d_in[6];
  const float* Wp = (const float*)d_in[7];
  const float* bp = (const float*)d_in[8];
  float* out = (float*)d_out;

  const int B = 2, T = 2048, C = 1024;
  const int M = B * T;                 // 4096
  const size_t MC = (size_t)M * C;
  const size_t CC = (size_t)C * C;

  char* p = (char*)d_ws;
  u16* xb  = (u16*)p;  p += MC * 2;    // reused as Y after QKV GEMM
  u16* Wqb = (u16*)p;  p += CC * 2;
  u16* Wkb = (u16*)p;  p += CC * 2;
  u16* Wvb = (u16*)p;  p += CC * 2;
  u16* Wpb = (u16*)p;  p += CC * 2;
  u16* Qbb = (u16*)p;  p += MC * 2;
  u16* Kbb = (u16*)p;  p += MC * 2;
  u16* Vbb = (u16*)p;  p += MC * 2;
  float* cosT = (float*)p; p += (size_t)T * 32 * 4;
  float* sinT = (float*)p; p += (size_t)T * 32 * 4;

  rope_table<<<T * 32 / 256, 256, 0, stream>>>(cosT, sinT, T);
  const int n4x = (int)(MC / 4);
  const int n4tot = n4x + 4 * (int)(CC / 4);
  cvt_all<<<n4tot / 256, 256, 0, stream>>>(x, Wq, Wk, Wv, Wp, xb, Wqb, Wkb, Wvb, Wpb, n4x);

  dim3 gq(24, M / 128);
  gemm_qkv<<<gq, 256, 0, stream>>>(xb, Wqb, Wkb, Wvb, bq, bk, bv, cosT, sinT, Qbb, Kbb, Vbb);

  dim3 fg(T / 64, B * 16);
  flash_mfma<<<fg, 256, 0, stream>>>(Qbb, Kbb, Vbb, xb);   // Y -> xb (reuse)

  dim3 gp(C / 64, M / 128);
  gemm_proj<<<gp, 256, 0, stream>>>(xb, Wpb, bp, out);
}

// Round 4
// 155.668 us; speedup vs baseline: 7.7362x; 1.0052x over previous
//
#include <hip/hip_runtime.h>
#include <math.h>

typedef unsigned short u16;
typedef unsigned int u32;
typedef __attribute__((ext_vector_type(8))) short short8;
typedef __attribute__((ext_vector_type(4))) float f32x4;
typedef __attribute__((ext_vector_type(4))) u16 u16x4;

#define AS1 __attribute__((address_space(1)))
#define AS3 __attribute__((address_space(3)))

// 0.125 * log2(e): QK^T scores scaled so softmax = exp2
#define QSCALE 0.18033688011112042f

__device__ __forceinline__ u16 f2bf(float f) {
  union { float f; u32 i; } u; u.f = f;
  u32 r = u.i + 0x7FFFu + ((u.i >> 16) & 1u);
  return (u16)(r >> 16);
}

__device__ __forceinline__ u32 pk_bf16(float a, float b) {
  u32 r;
  asm volatile("v_cvt_pk_bf16_f32 %0, %1, %2" : "=v"(r) : "v"(a), "v"(b));
  return r;
}

__device__ __forceinline__ void gl_lds16(const void* g, void* l) {
  __builtin_amdgcn_global_load_lds((const AS1 u32*)g, (AS3 u32*)l, 16, 0, 0);
}

// ---------------- RoPE table ----------------
__global__ void rope_table(float* __restrict__ cosT, float* __restrict__ sinT, int T) {
  int i = blockIdx.x * 256 + threadIdx.x;
  if (i >= T * 32) return;
  int t = i >> 5, j = i & 31;
  float inv = powf(10000.0f, -(float)j / 32.0f);
  float ang = (float)t * inv;
  cosT[i] = cosf(ang);
  sinT[i] = sinf(ang);
}

// ---------------- fused fp32 -> bf16 convert (x + 4 weights) ----------------
__global__ void cvt_all(const float* __restrict__ x,
                        const float* __restrict__ Wq, const float* __restrict__ Wk,
                        const float* __restrict__ Wv, const float* __restrict__ Wp,
                        u16* __restrict__ xb,
                        u16* __restrict__ Wqb, u16* __restrict__ Wkb,
                        u16* __restrict__ Wvb, u16* __restrict__ Wpb,
                        int n4x) {
  int i = blockIdx.x * 256 + threadIdx.x;
  const float* src; u16* dst; int off;
  if (i < n4x) { src = x; dst = xb; off = i; }
  else {
    int wi = i - n4x;
    int sel = wi >> 18;            // CC/4 = 2^18
    off = wi & ((1 << 18) - 1);
    src = sel == 0 ? Wq : sel == 1 ? Wk : sel == 2 ? Wv : Wp;
    dst = sel == 0 ? Wqb : sel == 1 ? Wkb : sel == 2 ? Wvb : Wpb;
  }
  float4 v = ((const float4*)src)[off];
  u16x4 o = { f2bf(v.x), f2bf(v.y), f2bf(v.z), f2bf(v.w) };
  ((u16x4*)dst)[off] = o;
}

// ---------------- fused QKV GEMM (bf16 MFMA) with RoPE epilogue ----------------
// grid (24, 32): blockIdx.x = sel*8 + col-tile. Q pre-scaled by QSCALE.
__global__ __launch_bounds__(256, 2) void gemm_qkv(
    const u16* __restrict__ xb,
    const u16* __restrict__ Wqb, const u16* __restrict__ Wkb, const u16* __restrict__ Wvb,
    const float* __restrict__ bq, const float* __restrict__ bk, const float* __restrict__ bv,
    const float* __restrict__ cosT, const float* __restrict__ sinT,
    u16* __restrict__ Qb, u16* __restrict__ Kb, u16* __restrict__ Vb) {
  const int K = 1024, N = 1024;
  __shared__ __attribute__((aligned(16))) u16 As[128 * 32];
  __shared__ __attribute__((aligned(16))) u16 Bs[128 * 32];
  const int tid = threadIdx.x;
  const int lane = tid & 63;
  const int hi = lane >> 4, cc = lane & 15;
  const int w = tid >> 6, wm = w >> 1, wn = w & 1;
  const int sel = blockIdx.x >> 3;
  const int row0 = blockIdx.y * 128, col0 = (blockIdx.x & 7) * 128;
  const u16* W = sel == 0 ? Wqb : sel == 1 ? Wkb : Wvb;
  const float* bias = sel == 0 ? bq : sel == 1 ? bk : bv;
  u16* Out = sel == 0 ? Qb : sel == 1 ? Kb : Vb;

  const int lr = tid >> 2;
  const int lk = (tid & 3) * 8;
  const u16* Ag0 = xb + (size_t)(row0 + lr) * K + lk;
  const u16* Ag1 = xb + (size_t)(row0 + 64 + lr) * K + lk;
  const u16* Wg0 = W + (size_t)(col0 + lr) * K + lk;
  const u16* Wg1 = W + (size_t)(col0 + 64 + lr) * K + lk;
  u16* Al0 = As + tid * 8;
  u16* Al1 = As + 2048 + tid * 8;
  u16* Bl0 = Bs + tid * 8;
  u16* Bl1 = Bs + 2048 + tid * 8;

  f32x4 acc[4][4];
#pragma unroll
  for (int m = 0; m < 4; ++m)
#pragma unroll
    for (int n = 0; n < 4; ++n) acc[m][n] = f32x4{0.f, 0.f, 0.f, 0.f};

  for (int k0 = 0; k0 < K; k0 += 32) {
    __syncthreads();
    gl_lds16(Ag0 + k0, Al0);
    gl_lds16(Ag1 + k0, Al1);
    gl_lds16(Wg0 + k0, Bl0);
    gl_lds16(Wg1 + k0, Bl1);
    __syncthreads();
    short8 a[4], b[4];
#pragma unroll
    for (int m = 0; m < 4; ++m)
      a[m] = *(const short8*)(As + (wm * 64 + m * 16 + cc) * 32 + hi * 8);
#pragma unroll
    for (int n = 0; n < 4; ++n)
      b[n] = *(const short8*)(Bs + (wn * 64 + n * 16 + cc) * 32 + hi * 8);
#pragma unroll
    for (int m = 0; m < 4; ++m)
#pragma unroll
      for (int n = 0; n < 4; ++n)
        acc[m][n] = __builtin_amdgcn_mfma_f32_16x16x32_bf16(a[m], b[n], acc[m][n], 0, 0, 0);
  }

  if (sel < 2) {
    const float qs = (sel == 0) ? QSCALE : 1.0f;
#pragma unroll
    for (int n = 0; n < 4; ++n) {
      const int col = col0 + wn * 64 + n * 16 + cc;
      const int j = (col & 63) >> 1;
      const float bb = bias[col];
#pragma unroll
      for (int m = 0; m < 4; ++m) {
        const int rw = row0 + wm * 64 + m * 16 + hi * 4;
#pragma unroll
        for (int r = 0; r < 4; ++r) {
          const int row = rw + r;
          const int t = row & 2047;
          float v = acc[m][n][r] + bb;
          float pv = __shfl_xor(v, 1);
          float c = cosT[t * 32 + j], s = sinT[t * 32 + j];
          float oo = (cc & 1) ? (s * pv + c * v) : (c * v - s * pv);
          Out[(size_t)row * N + col] = f2bf(oo * qs);
        }
      }
    }
  } else {
#pragma unroll
    for (int n = 0; n < 4; ++n) {
      const int col = col0 + wn * 64 + n * 16 + cc;
      const float bb = bias[col];
#pragma unroll
      for (int m = 0; m < 4; ++m) {
        const int rw = row0 + wm * 64 + m * 16 + hi * 4;
#pragma unroll
        for (int r = 0; r < 4; ++r)
          Out[(size_t)(rw + r) * N + col] = f2bf(acc[m][n][r] + bb);
      }
    }
  }
}

// ---------------- MFMA causal flash attention: 32 q rows/wave, 128 q/block ----------------
__global__ __launch_bounds__(256, 2) void flash_mfma(
    const u16* __restrict__ Qb, const u16* __restrict__ Kb,
    const u16* __restrict__ Vb, u16* __restrict__ Yb) {
  const int T = 2048, C = 1024;
  __shared__ __attribute__((aligned(16))) u16 Ks[64 * 64];       // [key][d] swizzled
  __shared__ __attribute__((aligned(16))) u16 Vt[64 * 64];       // [d][key] swizzled
  __shared__ __attribute__((aligned(16))) u16 Ps[4][32 * 64];    // per-wave P[q][key]

  const int tid = threadIdx.x;
  const int lane = tid & 63;
  const int hi = lane >> 4, cc = lane & 15;
  const int w = tid >> 6;
  const int qt = (int)gridDim.x - 1 - (int)blockIdx.x;  // longest first
  const int bh = blockIdx.y;
  const size_t hbase = (size_t)(bh >> 4) * T * C + (size_t)(bh & 15) * 64;
  const int q0 = qt * 128;
  const int q0w = q0 + w * 32;

  // Q fragments (B-operand; pre-scaled by QSCALE): [qh][kc2]
  short8 qa[2][2];
#pragma unroll
  for (int qh = 0; qh < 2; ++qh) {
    const u16* qp = Qb + hbase + (size_t)(q0w + qh * 16 + cc) * C + hi * 8;
    qa[qh][0] = *(const short8*)qp;
    qa[qh][1] = *(const short8*)(qp + 32);
  }

  f32x4 o[4][2];
#pragma unroll
  for (int nt = 0; nt < 4; ++nt)
#pragma unroll
    for (int qh = 0; qh < 2; ++qh) o[nt][qh] = f32x4{0.f, 0.f, 0.f, 0.f};
  float mrow[2] = {-1e30f, -1e30f};
  float lsum[2] = {0.f, 0.f};

  const int kkey = tid >> 2, kd0 = (tid & 3) * 16;
  const int vkp = tid & 31, vd0 = (tid >> 5) * 8;
  const u16* kgb = Kb + hbase + (size_t)kkey * C + kd0;
  const u16* vg0 = Vb + hbase + (size_t)(2 * vkp) * C + vd0;
  const u16* vg1 = Vb + hbase + (size_t)(2 * vkp + 1) * C + vd0;
  char* KsB = (char*)Ks;
  char* VtB = (char*)Vt;
  char* PsB = (char*)(Ps[w]);

  // prefetch tile 0
  short8 kv0 = *(const short8*)kgb;
  short8 kv1 = *(const short8*)(kgb + 8);
  short8 vv0 = *(const short8*)vg0;
  short8 vv1 = *(const short8*)vg1;

  const int nkt = 2 * qt + 2;
  const int ktmax_w = (q0w + 31) >> 6;   // last tile this wave computes

  for (int kt = 0; kt < nkt; ++kt) {
    __syncthreads();   // all waves done reading Ks/Vt
    {
      const int sw = (kkey & 7) << 4;
      const int base = kkey * 128 + kd0 * 2;
      *(short8*)(KsB + (base ^ sw)) = kv0;
      *(short8*)(KsB + ((base + 16) ^ sw)) = kv1;
    }
#pragma unroll
    for (int i = 0; i < 8; ++i) {
      const int d = vd0 + i;
      const u32 pv = (u32)(u16)vv0[i] | ((u32)(u16)vv1[i] << 16);
      *(u32*)(VtB + ((d * 128 + vkp * 4) ^ ((((d >> 3) ^ d) & 7) << 4)));
      *(u32*)(VtB + ((d * 128 + vkp * 4) ^ ((((d >> 3) ^ d) & 7) << 4))) = pv;
    }
    {  // prefetch next tile (clamped)
      const size_t koff = (size_t)((kt + 1 < nkt ? kt + 1 : kt) * 64) * C;
      kv0 = *(const short8*)(kgb + koff);
      kv1 = *(const short8*)(kgb + koff + 8);
      vv0 = *(const short8*)(vg0 + koff);
      vv1 = *(const short8*)(vg1 + koff);
    }
    __syncthreads();

    if (kt <= ktmax_w) {
      // K fragments, reused across both q halves
      short8 kf[4][2];
#pragma unroll
      for (int nt = 0; nt < 4; ++nt) {
        const int kr = nt * 16 + cc;
        const int sw2 = (kr & 7) << 4;
        kf[nt][0] = *(const short8*)(KsB + ((kr * 128 + hi * 16) ^ sw2));
        kf[nt][1] = *(const short8*)(KsB + ((kr * 128 + 64 + hi * 16) ^ sw2));
      }
      // S^T = K Q^T
      f32x4 s[4][2];
#pragma unroll
      for (int nt = 0; nt < 4; ++nt)
#pragma unroll
        for (int qh = 0; qh < 2; ++qh) {
          f32x4 z = f32x4{0.f, 0.f, 0.f, 0.f};
          z = __builtin_amdgcn_mfma_f32_16x16x32_bf16(kf[nt][0], qa[qh][0], z, 0, 0, 0);
          z = __builtin_amdgcn_mfma_f32_16x16x32_bf16(kf[nt][1], qa[qh][1], z, 0, 0, 0);
          s[nt][qh] = z;
        }

      if (kt * 64 + 63 > q0w) {   // diagonal region: mask key > q
#pragma unroll
        for (int qh = 0; qh < 2; ++qh) {
          const int qoff = q0w + qh * 16 + cc - kt * 64;
#pragma unroll
          for (int nt = 0; nt < 4; ++nt)
#pragma unroll
            for (int r = 0; r < 4; ++r) {
              const int key = nt * 16 + hi * 4 + r;
              if (key > qoff) s[nt][qh][r] = -1e30f;
            }
        }
      }

      // softmax (exp2 domain), per q half
#pragma unroll
      for (int qh = 0; qh < 2; ++qh) {
        float tm = s[0][qh][0];
#pragma unroll
        for (int nt = 0; nt < 4; ++nt)
#pragma unroll
          for (int r = 0; r < 4; ++r) tm = fmaxf(tm, s[nt][qh][r]);
        tm = fmaxf(tm, __shfl_xor(tm, 16));
        tm = fmaxf(tm, __shfl_xor(tm, 32));
        const float mnew = fmaxf(mrow[qh], tm);
        const float corr = exp2f(mrow[qh] - mnew);
        float p[16];
        float psum = 0.f;
#pragma unroll
        for (int nt = 0; nt < 4; ++nt)
#pragma unroll
          for (int r = 0; r < 4; ++r) {
            float e = exp2f(s[nt][qh][r] - mnew);
            p[nt * 4 + r] = e;
            psum += e;
          }
        psum += __shfl_xor(psum, 16);
        psum += __shfl_xor(psum, 32);
        lsum[qh] = lsum[qh] * corr + psum;
        mrow[qh] = mnew;
#pragma unroll
        for (int nt = 0; nt < 4; ++nt) o[nt][qh] *= corr;

        // pack + stage P[q][key]
        const int pr = qh * 16 + cc;
        const int psw = (pr & 7) << 4;
#pragma unroll
        for (int nt = 0; nt < 4; ++nt) {
          u32 w0 = pk_bf16(p[nt * 4 + 0], p[nt * 4 + 1]);
          u32 w1 = pk_bf16(p[nt * 4 + 2], p[nt * 4 + 3]);
          u32 pkd[2] = {w0, w1};
          *(u32*)(PsB + ((pr * 128 + nt * 32 + hi * 8) ^ psw)) = pkd[0];
          *(u32*)(PsB + ((pr * 128 + nt * 32 + hi * 8 + 4) ^ psw)) = pkd[1];
        }
      }

      // O^T += V^T P^T
#pragma unroll
      for (int kc = 0; kc < 2; ++kc) {
        short8 pa[2];
#pragma unroll
        for (int qh = 0; qh < 2; ++qh) {
          const int pr = qh * 16 + cc;
          pa[qh] = *(const short8*)(PsB + ((pr * 128 + kc * 64 + hi * 16) ^ ((pr & 7) << 4)));
        }
#pragma unroll
        for (int nt = 0; nt < 4; ++nt) {
          const int vr = nt * 16 + cc;
          short8 vb = *(const short8*)(VtB + ((vr * 128 + kc * 64 + hi * 16) ^ ((((vr >> 3) ^ vr) & 7) << 4)));
#pragma unroll
          for (int qh = 0; qh < 2; ++qh)
            o[nt][qh] = __builtin_amdgcn_mfma_f32_16x16x32_bf16(vb, pa[qh], o[nt][qh], 0, 0, 0);
        }
      }
    }
  }

#pragma unroll
  for (int qh = 0; qh < 2; ++qh) {
    const float invl = 1.0f / lsum[qh];
#pragma unroll
    for (int nt = 0; nt < 4; ++nt) {
      u16x4 y = { f2bf(o[nt][qh][0] * invl), f2bf(o[nt][qh][1] * invl),
                  f2bf(o[nt][qh][2] * invl), f2bf(o[nt][qh][3] * invl) };
      *(u16x4*)(Yb + hbase + (size_t)(q0w + qh * 16 + cc) * C + nt * 16 + hi * 4) = y;
    }
  }
}

// ---------------- proj GEMM: BN=64, fp32 out ----------------
__global__ __launch_bounds__(256, 2) void gemm_proj(
    const u16* __restrict__ A, const u16* __restrict__ W,
    const float* __restrict__ bias, float* __restrict__ Out) {
  const int K = 1024, N = 1024;
  __shared__ __attribute__((aligned(16))) u16 As[128 * 32];
  __shared__ __attribute__((aligned(16))) u16 Bs[64 * 32];
  const int tid = threadIdx.x;
  const int lane = tid & 63;
  const int hi = lane >> 4, cc = lane & 15;
  const int w = tid >> 6, wm = w >> 1, wn = w & 1;
  const int row0 = blockIdx.y * 128, col0 = blockIdx.x * 64;

  const int lr = tid >> 2;
  const int lk = (tid & 3) * 8;
  const u16* Ag0 = A + (size_t)(row0 + lr) * K + lk;
  const u16* Ag1 = A + (size_t)(row0 + 64 + lr) * K + lk;
  const u16* Wg0 = W + (size_t)(col0 + lr) * K + lk;
  u16* Al0 = As + tid * 8;
  u16* Al1 = As + 2048 + tid * 8;
  u16* Bl0 = Bs + tid * 8;

  f32x4 acc[4][2];
#pragma unroll
  for (int m = 0; m < 4; ++m)
#pragma unroll
    for (int n = 0; n < 2; ++n) acc[m][n] = f32x4{0.f, 0.f, 0.f, 0.f};

  for (int k0 = 0; k0 < K; k0 += 32) {
    __syncthreads();
    gl_lds16(Ag0 + k0, Al0);
    gl_lds16(Ag1 + k0, Al1);
    gl_lds16(Wg0 + k0, Bl0);
    __syncthreads();
    short8 a[4], b[2];
#pragma unroll
    for (int m = 0; m < 4; ++m)
      a[m] = *(const short8*)(As + (wm * 64 + m * 16 + cc) * 32 + hi * 8);
#pragma unroll
    for (int n = 0; n < 2; ++n)
      b[n] = *(const short8*)(Bs + (wn * 32 + n * 16 + cc) * 32 + hi * 8);
#pragma unroll
    for (int m = 0; m < 4; ++m)
#pragma unroll
      for (int n = 0; n < 2; ++n)
        acc[m][n] = __builtin_amdgcn_mfma_f32_16x16x32_bf16(a[m], b[n], acc[m][n], 0, 0, 0);
  }

#pragma unroll
  for (int n = 0; n < 2; ++n) {
    const int col = col0 + wn * 32 + n * 16 + cc;
    const float bb = bias[col];
#pragma unroll
    for (int m = 0; m < 4; ++m) {
      const int rw = row0 + wm * 64 + m * 16 + hi * 4;
#pragma unroll
      for (int r = 0; r < 4; ++r)
        Out[(size_t)(rw + r) * N + col] = acc[m][n][r] + bb;
    }
  }
}

extern "C" void kernel_launch(void* const* d_in, const int* in_sizes, int n_in,
                              void* d_out, int out_size, void* d_ws, size_t ws_size,
                              hipStream_t stream) {
  const float* x  = (const float*)d_in[0];
  const float* Wq = (const float*)d_in[1];
  const float* bq = (const float*)d_in[2];
  const float* Wk = (const float*)d_in[3];
  const float* bk = (const float*)d_in[4];
  const float* Wv = (const float*)d_in[5];
  const float* bv = (const float*)d_in[6];
  const float* Wp = (const float*)d_in[7];
  const float* bp = (const float*)d_in[8];
  float* out = (float*)d_out;

  const int B = 2, T = 2048, C = 1024;
  const int M = B * T;
  const size_t MC = (size_t)M * C;
  const size_t CC = (size_t)C * C;

  char* p = (char*)d_ws;
  u16* xb  = (u16*)p;  p += MC * 2;    // reused as Y after QKV GEMM
  u16* Wqb = (u16*)p;  p += CC * 2;
  u16* Wkb = (u16*)p;  p += CC * 2;
  u16* Wvb = (u16*)p;  p += CC * 2;
  u16* Wpb = (u16*)p;  p += CC * 2;
  u16* Qbb = (u16*)p;  p += MC * 2;
  u16* Kbb = (u16*)p;  p += MC * 2;
  u16* Vbb = (u16*)p;  p += MC * 2;
  float* cosT = (float*)p; p += (size_t)T * 32 * 4;
  float* sinT = (float*)p; p += (size_t)T * 32 * 4;

  rope_table<<<T * 32 / 256, 256, 0, stream>>>(cosT, sinT, T);
  const int n4x = (int)(MC / 4);
  const int n4tot = n4x + 4 * (int)(CC / 4);
  cvt_all<<<n4tot / 256, 256, 0, stream>>>(x, Wq, Wk, Wv, Wp, xb, Wqb, Wkb, Wvb, Wpb, n4x);

  dim3 gq(24, M / 128);
  gemm_qkv<<<gq, 256, 0, stream>>>(xb, Wqb, Wkb, Wvb, bq, bk, bv, cosT, sinT, Qbb, Kbb, Vbb);

  dim3 fg(T / 128, B * 16);
  flash_mfma<<<fg, 256, 0, stream>>>(Qbb, Kbb, Vbb, xb);   // Y -> xb (reuse)

  dim3 gp(C / 64, M / 128);
  gemm_proj<<<gp, 256, 0, stream>>>(xb, Wpb, bp, out);
}